// Round 3
// baseline (37.511 us; speedup 1.0000x reference)
//
#include <hip/hip_runtime.h>
#include <math.h>

#define WAVES_PER_BLOCK 4   // 256 threads; 1 batch element per wave (wave-uniform b)

__device__ __forceinline__ float log_sigmoid_fast(float x) {
    // log(sigmoid(x)) = min(x,0) - log(1 + exp(-|x|))
    return fminf(x, 0.0f) - __logf(1.0f + __expf(-fabsf(x)));
}

__global__ __launch_bounds__(256) void cbow_partial_kernel(
    const int* __restrict__ context,      // (B, 10)
    const int* __restrict__ target,       // (B,)
    const int* __restrict__ neg_targets,  // (B, 10)
    const float* __restrict__ W_in,       // (V, 128)
    const float* __restrict__ W_out,      // (V, 128)
    float* __restrict__ partial,          // (gridDim.x,)
    int B)
{
    const int lane = threadIdx.x & 63;
    // wave id is wave-uniform; readfirstlane pins it to an SGPR
    const int wave = __builtin_amdgcn_readfirstlane(threadIdx.x >> 6);
    int b = blockIdx.x * WAVES_PER_BLOCK + wave;      // uniform per wave
    const bool valid = (b < B);
    if (!valid) b = 0;

    const float2* __restrict__ Win2  = (const float2*)W_in;   // row stride 64 float2
    const float2* __restrict__ Wout2 = (const float2*)W_out;

    // ---- 21 indices, all wave-uniform -> SGPRs (scalar loads, no VGPR cost) ----
    int cidx[10], nidx[10], tidx;
    #pragma unroll
    for (int c = 0; c < 10; ++c)
        cidx[c] = __builtin_amdgcn_readfirstlane(context[b * 10 + c]);
    tidx = __builtin_amdgcn_readfirstlane(target[b]);
    #pragma unroll
    for (int k = 0; k < 10; ++k)
        nidx[k] = __builtin_amdgcn_readfirstlane(neg_targets[b * 10 + k]);

    // ---- 21 row gathers, saddr form: SGPR base per row + shared lane offset ----
    // lane holds dims [2*lane, 2*lane+1]; all loads issued back-to-back, in flight
    float2 cr[10];
    #pragma unroll
    for (int c = 0; c < 10; ++c)
        cr[c] = Win2[(size_t)cidx[c] * 64 + lane];
    float2 orow[11];
    orow[0] = Wout2[(size_t)tidx * 64 + lane];
    #pragma unroll
    for (int k = 0; k < 10; ++k)
        orow[1 + k] = Wout2[(size_t)nidx[k] * 64 + lane];

    // ---- h = mean of context rows ----
    float hx = 0.f, hy = 0.f;
    #pragma unroll
    for (int c = 0; c < 10; ++c) { hx += cr[c].x; hy += cr[c].y; }
    hx *= 0.1f; hy *= 0.1f;

    // ---- 11 dot-product partials ----
    float s[11];
    #pragma unroll
    for (int i = 0; i < 11; ++i)
        s[i] = hx * orow[i].x + hy * orow[i].y;

    // ---- full 64-lane butterfly reduce of all 11 partials ----
    #pragma unroll
    for (int off = 32; off > 0; off >>= 1) {
        #pragma unroll
        for (int i = 0; i < 11; ++i)
            s[i] += __shfl_xor(s[i], off, 64);
    }

    float loss = log_sigmoid_fast(s[0]);
    #pragma unroll
    for (int k = 0; k < 10; ++k)
        loss += log_sigmoid_fast(-s[1 + k]);
    if (!valid) loss = 0.f;

    __shared__ float wsum[WAVES_PER_BLOCK];
    if (lane == 0) wsum[wave] = loss;
    __syncthreads();
    if (threadIdx.x == 0) {
        float t = 0.f;
        #pragma unroll
        for (int w = 0; w < WAVES_PER_BLOCK; ++w) t += wsum[w];
        partial[blockIdx.x] = t;
    }
}

__global__ __launch_bounds__(256) void reduce_partials_kernel(
    const float* __restrict__ partial, int n, float* __restrict__ out, float scale)
{
    __shared__ float sm[4];
    float t = 0.f;
    for (int i = threadIdx.x; i < n; i += 256) t += partial[i];
    #pragma unroll
    for (int off = 32; off > 0; off >>= 1) t += __shfl_xor(t, off, 64);
    const int lane = threadIdx.x & 63;
    const int wave = threadIdx.x >> 6;
    if (lane == 0) sm[wave] = t;
    __syncthreads();
    if (threadIdx.x == 0) {
        out[0] = (sm[0] + sm[1] + sm[2] + sm[3]) * scale;
    }
}

extern "C" void kernel_launch(void* const* d_in, const int* in_sizes, int n_in,
                              void* d_out, int out_size, void* d_ws, size_t ws_size,
                              hipStream_t stream) {
    const int* context     = (const int*)d_in[0];
    const int* target      = (const int*)d_in[1];
    const int* neg_targets = (const int*)d_in[2];
    const float* W_in      = (const float*)d_in[3];
    const float* W_out     = (const float*)d_in[4];
    float* out = (float*)d_out;

    const int B = in_sizes[1];                                    // 16384
    const int nblocks = (B + WAVES_PER_BLOCK - 1) / WAVES_PER_BLOCK;  // 4096

    float* partial = (float*)d_ws;

    cbow_partial_kernel<<<nblocks, 256, 0, stream>>>(
        context, target, neg_targets, W_in, W_out, partial, B);

    reduce_partials_kernel<<<1, 256, 0, stream>>>(
        partial, nblocks, out, -1.0f / (float)B);
}